// Round 1
// baseline (1096.400 us; speedup 1.0000x reference)
//
#include <hip/hip_runtime.h>

#define HWD 262144   // H*W*D
#define WD  4096     // W*D

// ---------------- v = Wv·x + bv  (GEMM M=128, K=128, N=262144) ----------------
__global__ __launch_bounds__(256) void conv_v_kernel(
    const float* __restrict__ x, const float* __restrict__ Wv,
    const float* __restrict__ bv, float* __restrict__ v)
{
    __shared__ float Xs[16][64];    // k-chunk x n
    __shared__ float Ws[16][132];   // k-chunk x o (transposed), pitch mult-of-4
    const int tid = threadIdx.x;
    const int n0  = blockIdx.x * 64;
    const int og  = tid >> 4, ng = tid & 15;
    const int o0  = og * 8,  nn0 = ng * 4;
    float acc[8][4];
#pragma unroll
    for (int r = 0; r < 8; ++r) {
        const float b = bv[o0 + r];
        acc[r][0] = b; acc[r][1] = b; acc[r][2] = b; acc[r][3] = b;
    }
    for (int k0 = 0; k0 < 128; k0 += 16) {
        __syncthreads();
#pragma unroll
        for (int i = 0; i < 4; ++i) {
            const int e = tid + i * 256;
            Xs[e >> 6][e & 63] = x[(k0 + (e >> 6)) * HWD + n0 + (e & 63)];
        }
#pragma unroll
        for (int i = 0; i < 8; ++i) {
            const int e = tid + i * 256;          // e = kk*128 + o
            Ws[e >> 7][e & 127] = Wv[(e & 127) * 128 + k0 + (e >> 7)];
        }
        __syncthreads();
#pragma unroll
        for (int kk = 0; kk < 16; ++kk) {
            const float4 xv = *(const float4*)&Xs[kk][nn0];
            const float4 wa = *(const float4*)&Ws[kk][o0];
            const float4 wb = *(const float4*)&Ws[kk][o0 + 4];
            const float w[8] = {wa.x, wa.y, wa.z, wa.w, wb.x, wb.y, wb.z, wb.w};
#pragma unroll
            for (int r = 0; r < 8; ++r) {
                acc[r][0] += w[r] * xv.x; acc[r][1] += w[r] * xv.y;
                acc[r][2] += w[r] * xv.z; acc[r][3] += w[r] * xv.w;
            }
        }
    }
#pragma unroll
    for (int r = 0; r < 8; ++r)
        *(float4*)&v[(o0 + r) * HWD + n0 + nn0] =
            make_float4(acc[r][0], acc[r][1], acc[r][2], acc[r][3]);
}

// ---------------- q = Wq·x + bq (y-block: k = Wk·y + bk), M=16 ----------------
__global__ __launch_bounds__(256) void conv_qk_kernel(
    const float* __restrict__ x, const float* __restrict__ y,
    const float* __restrict__ Wq, const float* __restrict__ bq,
    const float* __restrict__ Wk, const float* __restrict__ bk,
    float* __restrict__ q, float* __restrict__ k)
{
    const float* src; const float* W; const float* b; float* dst;
    if (blockIdx.y == 0) { src = x; W = Wq; b = bq; dst = q; }
    else                 { src = y; W = Wk; b = bk; dst = k; }
    __shared__ float Ws[16][132];   // [o][c]
    const int tid = threadIdx.x;
#pragma unroll
    for (int i = 0; i < 8; ++i) {
        const int e = tid + i * 256;              // e = o*128 + c
        Ws[e >> 7][e & 127] = W[e];
    }
    __syncthreads();
    const int n = blockIdx.x * 512 + tid * 2;
    float acc[16][2];
#pragma unroll
    for (int o = 0; o < 16; ++o) { acc[o][0] = b[o]; acc[o][1] = b[o]; }
    for (int c0 = 0; c0 < 128; c0 += 4) {
        float2 xv[4];
#pragma unroll
        for (int j = 0; j < 4; ++j) xv[j] = *(const float2*)&src[(c0 + j) * HWD + n];
#pragma unroll
        for (int o = 0; o < 16; ++o) {
            const float4 w = *(const float4*)&Ws[o][c0];
            acc[o][0] += w.x * xv[0].x + w.y * xv[1].x + w.z * xv[2].x + w.w * xv[3].x;
            acc[o][1] += w.x * xv[0].y + w.y * xv[1].y + w.z * xv[2].y + w.w * xv[3].y;
        }
    }
#pragma unroll
    for (int o = 0; o < 16; ++o)
        *(float2*)&dst[o * HWD + n] = make_float2(acc[o][0], acc[o][1]);
}

// ---------------- fused W+D attention: block (s=bx, hh=by) --------------------
// Writes out = gamma*(T_W + T_D) + x on slab (cc in {2s,2s+1}, hh, :, :)
__global__ __launch_bounds__(256) void cc_wd_kernel(
    const float* __restrict__ q, const float* __restrict__ k,
    const float* __restrict__ v, const float* __restrict__ x,
    const float* __restrict__ gamma, float* __restrict__ out)
{
    const int s   = blockIdx.x;
    const int hh  = blockIdx.y;
    const int tid = threadIdx.x;
    __shared__ float qs[16][64];
    __shared__ float ks[16][64];
    __shared__ float EA[64][68];    // E, then A^T (pitch 68: 16B-aligned rows)
    __shared__ float Vs[128][68];
    __shared__ float red[4][64];
    float acc[8][4];
#pragma unroll
    for (int r = 0; r < 8; ++r) { acc[r][0] = 0; acc[r][1] = 0; acc[r][2] = 0; acc[r][3] = 0; }

    const int og = tid >> 4, ng = tid & 15;
    const int dd0 = ng * 4;          // output col group; rows c = og + 16*r (interleaved)

    for (int phase = 0; phase < 2; ++phase) {
        const int base   = hh * WD + (phase == 0 ? s : s * 64);
        const int stride = (phase == 0) ? 64 : 1;
        __syncthreads();
#pragma unroll
        for (int i = 0; i < 4; ++i) {
            const int e = tid + i * 256, c = e >> 6, j = e & 63;
            qs[c][j] = q[c * HWD + base + j * stride];
            ks[c][j] = k[c * HWD + base + j * stride];
        }
        __syncthreads();
        {   // E[i][j] = sum_c qs[c][i] * ks[c][j]
            const int irow = tid >> 2;
            const int j0   = (tid & 3) * 16;
            float qr[16];
#pragma unroll
            for (int c = 0; c < 16; ++c) qr[c] = qs[c][irow];
#pragma unroll
            for (int jj = 0; jj < 16; ++jj) {
                const int j = j0 + jj;
                float e = 0.f;
#pragma unroll
                for (int c = 0; c < 16; ++c) e += qr[c] * ks[c][j];
                EA[irow][j] = e;
            }
        }
        __syncthreads();
        {   // softmax over rows i, per column j; write transposed: EA[j][i]
            const int j = tid & 63, seg = tid >> 6;
            float vals[16];
            float m = -1e30f;
#pragma unroll
            for (int i = 0; i < 16; ++i) { vals[i] = EA[seg * 16 + i][j]; m = fmaxf(m, vals[i]); }
            red[seg][j] = m;
            __syncthreads();
            m = fmaxf(fmaxf(red[0][j], red[1][j]), fmaxf(red[2][j], red[3][j]));
            float ss = 0.f;
#pragma unroll
            for (int i = 0; i < 16; ++i) { vals[i] = __expf(vals[i] - m); ss += vals[i]; }
            __syncthreads();
            red[seg][j] = ss;
            __syncthreads();
            ss = red[0][j] + red[1][j] + red[2][j] + red[3][j];
            const float inv = 1.f / ss;
#pragma unroll
            for (int i = 0; i < 16; ++i) EA[j][seg * 16 + i] = vals[i] * inv;
        }
        // V slice (no barrier needed before: different buffer)
#pragma unroll
        for (int i = 0; i < 32; ++i) {
            const int e = tid + i * 256, c = e >> 6, j = e & 63;
            Vs[c][j] = v[c * HWD + base + j * stride];
        }
        __syncthreads();
        // R[c][dd] += sum_j Vs[c][j] * A(dd,j), A(dd,j) stored at EA[j][dd]
        for (int j = 0; j < 64; j += 4) {
            const float4 a0 = *(const float4*)&EA[j + 0][dd0];
            const float4 a1 = *(const float4*)&EA[j + 1][dd0];
            const float4 a2 = *(const float4*)&EA[j + 2][dd0];
            const float4 a3 = *(const float4*)&EA[j + 3][dd0];
#pragma unroll
            for (int r = 0; r < 8; ++r) {
                const float4 vv = *(const float4*)&Vs[og + 16 * r][j];
                acc[r][0] += vv.x * a0.x + vv.y * a1.x + vv.z * a2.x + vv.w * a3.x;
                acc[r][1] += vv.x * a0.y + vv.y * a1.y + vv.z * a2.y + vv.w * a3.y;
                acc[r][2] += vv.x * a0.z + vv.y * a1.z + vv.z * a2.z + vv.w * a3.z;
                acc[r][3] += vv.x * a0.w + vv.y * a1.w + vv.z * a2.w + vv.w * a3.w;
            }
        }
    }
    const float g = gamma[0];
#pragma unroll
    for (int r = 0; r < 8; ++r) {
        const int c = og + 16 * r;
        const int o = (2 * s + (c >> 6)) * HWD + hh * WD + (c & 63) * 64 + dd0;
        const float4 xr = *(const float4*)&x[o];
        *(float4*)&out[o] = make_float4(g * acc[r][0] + xr.x, g * acc[r][1] + xr.y,
                                        g * acc[r][2] + xr.z, g * acc[r][3] + xr.w);
    }
}

// ---------------- fused H attention: block (t=bx, ww=by) ----------------------
// out += gamma*T_H on slab (cc in {2t,2t+1}, :, ww, :). Diagonal of E masked.
__global__ __launch_bounds__(256) void cc_h_kernel(
    const float* __restrict__ q, const float* __restrict__ k,
    const float* __restrict__ v, const float* __restrict__ gamma,
    float* __restrict__ out)
{
    const int t   = blockIdx.x;
    const int ww  = blockIdx.y;
    const int tid = threadIdx.x;
    __shared__ float qs[16][64];
    __shared__ float ks[16][64];
    __shared__ float EA[64][68];
    __shared__ float Vs[128][68];
    __shared__ float red[4][64];
    float acc[8][4];
#pragma unroll
    for (int r = 0; r < 8; ++r) { acc[r][0] = 0; acc[r][1] = 0; acc[r][2] = 0; acc[r][3] = 0; }

    const int og = tid >> 4, ng = tid & 15;
    const int dd0 = ng * 4;
    const int base = ww * 64 + t;   // element [c][i] at c*HWD + i*WD + base

#pragma unroll
    for (int i = 0; i < 4; ++i) {
        const int e = tid + i * 256, c = e >> 6, j = e & 63;
        qs[c][j] = q[c * HWD + j * WD + base];
        ks[c][j] = k[c * HWD + j * WD + base];
    }
    __syncthreads();
    {
        const int irow = tid >> 2;
        const int j0   = (tid & 3) * 16;
        float qr[16];
#pragma unroll
        for (int c = 0; c < 16; ++c) qr[c] = qs[c][irow];
#pragma unroll
        for (int jj = 0; jj < 16; ++jj) {
            const int j = j0 + jj;
            float e = 0.f;
#pragma unroll
            for (int c = 0; c < 16; ++c) e += qr[c] * ks[c][j];
            if (irow == j) e = -1e30f;       // diagonal -inf mask
            EA[irow][j] = e;
        }
    }
    __syncthreads();
    {
        const int j = tid & 63, seg = tid >> 6;
        float vals[16];
        float m = -1e30f;
#pragma unroll
        for (int i = 0; i < 16; ++i) { vals[i] = EA[seg * 16 + i][j]; m = fmaxf(m, vals[i]); }
        red[seg][j] = m;
        __syncthreads();
        m = fmaxf(fmaxf(red[0][j], red[1][j]), fmaxf(red[2][j], red[3][j]));
        float ss = 0.f;
#pragma unroll
        for (int i = 0; i < 16; ++i) { vals[i] = __expf(vals[i] - m); ss += vals[i]; }
        __syncthreads();
        red[seg][j] = ss;
        __syncthreads();
        ss = red[0][j] + red[1][j] + red[2][j] + red[3][j];
        const float inv = 1.f / ss;
#pragma unroll
        for (int i = 0; i < 16; ++i) EA[j][seg * 16 + i] = vals[i] * inv;
    }
#pragma unroll
    for (int i = 0; i < 32; ++i) {
        const int e = tid + i * 256, c = e >> 6, j = e & 63;
        Vs[c][j] = v[c * HWD + j * WD + base];
    }
    __syncthreads();
    for (int j = 0; j < 64; j += 4) {
        const float4 a0 = *(const float4*)&EA[j + 0][dd0];
        const float4 a1 = *(const float4*)&EA[j + 1][dd0];
        const float4 a2 = *(const float4*)&EA[j + 2][dd0];
        const float4 a3 = *(const float4*)&EA[j + 3][dd0];
#pragma unroll
        for (int r = 0; r < 8; ++r) {
            const float4 vv = *(const float4*)&Vs[og + 16 * r][j];
            acc[r][0] += vv.x * a0.x + vv.y * a1.x + vv.z * a2.x + vv.w * a3.x;
            acc[r][1] += vv.x * a0.y + vv.y * a1.y + vv.z * a2.y + vv.w * a3.y;
            acc[r][2] += vv.x * a0.z + vv.y * a1.z + vv.z * a2.z + vv.w * a3.z;
            acc[r][3] += vv.x * a0.w + vv.y * a1.w + vv.z * a2.w + vv.w * a3.w;
        }
    }
    const float g = gamma[0];
#pragma unroll
    for (int r = 0; r < 8; ++r) {
        const int c = og + 16 * r;
        const int o = (2 * t + (c >> 6)) * HWD + (c & 63) * WD + ww * 64 + dd0;
        float4 pr = *(const float4*)&out[o];
        pr.x += g * acc[r][0]; pr.y += g * acc[r][1];
        pr.z += g * acc[r][2]; pr.w += g * acc[r][3];
        *(float4*)&out[o] = pr;
    }
}

extern "C" void kernel_launch(void* const* d_in, const int* in_sizes, int n_in,
                              void* d_out, int out_size, void* d_ws, size_t ws_size,
                              hipStream_t stream)
{
    const float* x     = (const float*)d_in[0];
    const float* y     = (const float*)d_in[1];
    const float* Wq    = (const float*)d_in[2];
    const float* bq    = (const float*)d_in[3];
    const float* Wk    = (const float*)d_in[4];
    const float* bk    = (const float*)d_in[5];
    const float* Wv    = (const float*)d_in[6];
    const float* bv    = (const float*)d_in[7];
    const float* gamma = (const float*)d_in[8];
    float* out = (float*)d_out;

    float* v = (float*)d_ws;                       // 128*HWD floats
    float* q = v + (size_t)128 * HWD;              // 16*HWD
    float* k = q + (size_t)16 * HWD;               // 16*HWD  (total 160 MiB)

    conv_v_kernel <<<4096, 256, 0, stream>>>(x, Wv, bv, v);
    conv_qk_kernel<<<dim3(512, 2), 256, 0, stream>>>(x, y, Wq, bq, Wk, bk, q, k);
    cc_wd_kernel  <<<dim3(64, 64), 256, 0, stream>>>(q, k, v, x, gamma, out);
    cc_h_kernel   <<<dim3(64, 64), 256, 0, stream>>>(q, k, v, gamma, out);
}

// Round 2
// 766.795 us; speedup vs baseline: 1.4298x; 1.4298x over previous
//
#include <hip/hip_runtime.h>

#define HWD 262144   // H*W*D
#define WD  4096     // W*D

typedef unsigned short bf16_t;
struct __align__(8) us4 { unsigned short x, y, z, w; };

__device__ inline float b2f(unsigned short u) {
    return __uint_as_float(((unsigned int)u) << 16);
}
__device__ inline unsigned short f2b(float f) {
    unsigned int u = __float_as_uint(f);
    u += 0x7fff + ((u >> 16) & 1);          // round-to-nearest-even
    return (unsigned short)(u >> 16);
}

// ---------------- v = Wv·x + bv  (GEMM M=128, K=128, N=262144), bf16 out -----
__global__ __launch_bounds__(256) void conv_v_kernel(
    const float* __restrict__ x, const float* __restrict__ Wv,
    const float* __restrict__ bv, bf16_t* __restrict__ v)
{
    __shared__ float Xs[16][64];
    __shared__ float Ws[16][132];
    const int tid = threadIdx.x;
    const int n0  = blockIdx.x * 64;
    const int og  = tid >> 4, ng = tid & 15;
    const int o0  = og * 8,  nn0 = ng * 4;
    float acc[8][4];
#pragma unroll
    for (int r = 0; r < 8; ++r) {
        const float b = bv[o0 + r];
        acc[r][0] = b; acc[r][1] = b; acc[r][2] = b; acc[r][3] = b;
    }
    for (int k0 = 0; k0 < 128; k0 += 16) {
        __syncthreads();
#pragma unroll
        for (int i = 0; i < 4; ++i) {
            const int e = tid + i * 256;
            Xs[e >> 6][e & 63] = x[(k0 + (e >> 6)) * HWD + n0 + (e & 63)];
        }
#pragma unroll
        for (int i = 0; i < 8; ++i) {
            const int e = tid + i * 256;
            Ws[e >> 7][e & 127] = Wv[(e & 127) * 128 + k0 + (e >> 7)];
        }
        __syncthreads();
#pragma unroll
        for (int kk = 0; kk < 16; ++kk) {
            const float4 xv = *(const float4*)&Xs[kk][nn0];
            const float4 wa = *(const float4*)&Ws[kk][o0];
            const float4 wb = *(const float4*)&Ws[kk][o0 + 4];
            const float w[8] = {wa.x, wa.y, wa.z, wa.w, wb.x, wb.y, wb.z, wb.w};
#pragma unroll
            for (int r = 0; r < 8; ++r) {
                acc[r][0] += w[r] * xv.x; acc[r][1] += w[r] * xv.y;
                acc[r][2] += w[r] * xv.z; acc[r][3] += w[r] * xv.w;
            }
        }
    }
#pragma unroll
    for (int r = 0; r < 8; ++r) {
        us4 o; o.x = f2b(acc[r][0]); o.y = f2b(acc[r][1]);
        o.z = f2b(acc[r][2]); o.w = f2b(acc[r][3]);
        *(us4*)&v[(size_t)(o0 + r) * HWD + n0 + nn0] = o;
    }
}

// ---------------- q = Wq·x + bq (y-block: k = Wk·y + bk), bf16 out -----------
__global__ __launch_bounds__(256) void conv_qk_kernel(
    const float* __restrict__ x, const float* __restrict__ y,
    const float* __restrict__ Wq, const float* __restrict__ bq,
    const float* __restrict__ Wk, const float* __restrict__ bk,
    bf16_t* __restrict__ q, bf16_t* __restrict__ k)
{
    const float* src; const float* W; const float* b; bf16_t* dst;
    if (blockIdx.y == 0) { src = x; W = Wq; b = bq; dst = q; }
    else                 { src = y; W = Wk; b = bk; dst = k; }
    __shared__ float Ws[16][132];
    const int tid = threadIdx.x;
#pragma unroll
    for (int i = 0; i < 8; ++i) {
        const int e = tid + i * 256;
        Ws[e >> 7][e & 127] = W[e];
    }
    __syncthreads();
    const int n = blockIdx.x * 512 + tid * 2;
    float acc[16][2];
#pragma unroll
    for (int o = 0; o < 16; ++o) { acc[o][0] = b[o]; acc[o][1] = b[o]; }
    for (int c0 = 0; c0 < 128; c0 += 4) {
        float2 xv[4];
#pragma unroll
        for (int j = 0; j < 4; ++j) xv[j] = *(const float2*)&src[(c0 + j) * HWD + n];
#pragma unroll
        for (int o = 0; o < 16; ++o) {
            const float4 w = *(const float4*)&Ws[o][c0];
            acc[o][0] += w.x * xv[0].x + w.y * xv[1].x + w.z * xv[2].x + w.w * xv[3].x;
            acc[o][1] += w.x * xv[0].y + w.y * xv[1].y + w.z * xv[2].y + w.w * xv[3].y;
        }
    }
#pragma unroll
    for (int o = 0; o < 16; ++o) {
        unsigned int p = (unsigned int)f2b(acc[o][0]) |
                         ((unsigned int)f2b(acc[o][1]) << 16);
        *(unsigned int*)&dst[(size_t)o * HWD + n] = p;
    }
}

// ------------- transpose (w<->d): dst[c][h][d][w] = src[c][h][w][d] ----------
__global__ __launch_bounds__(256) void t_wd_kernel(
    const bf16_t* __restrict__ src, bf16_t* __restrict__ dst)
{
    const int h = blockIdx.x, c = blockIdx.y;
    __shared__ bf16_t tile[64][68];
    const size_t base = (size_t)c * HWD + h * WD;
    const int tid = threadIdx.x;
#pragma unroll
    for (int i = 0; i < 4; ++i) {
        const int f = (tid + i * 256) * 4;
        const int w = f >> 6, d = f & 63;
        const us4 val = *(const us4*)&src[base + w * 64 + d];
        tile[w][d] = val.x; tile[w][d + 1] = val.y;
        tile[w][d + 2] = val.z; tile[w][d + 3] = val.w;
    }
    __syncthreads();
#pragma unroll
    for (int i = 0; i < 4; ++i) {
        const int f = (tid + i * 256) * 4;
        const int d = f >> 6, w0 = f & 63;
        us4 o; o.x = tile[w0][d]; o.y = tile[w0 + 1][d];
        o.z = tile[w0 + 2][d]; o.w = tile[w0 + 3][d];
        *(us4*)&dst[base + d * 64 + w0] = o;
    }
}

// ------------- permute: dst[c][w][d][h] = src[c][h][w][d] --------------------
__global__ __launch_bounds__(256) void t_hd_kernel(
    const bf16_t* __restrict__ src, bf16_t* __restrict__ dst)
{
    const int w = blockIdx.x, c = blockIdx.y;
    __shared__ bf16_t tile[64][68];
    const size_t cb = (size_t)c * HWD;
    const int tid = threadIdx.x;
#pragma unroll
    for (int i = 0; i < 4; ++i) {
        const int f = (tid + i * 256) * 4;
        const int h = f >> 6, d0 = f & 63;
        const us4 val = *(const us4*)&src[cb + h * WD + w * 64 + d0];
        tile[h][d0] = val.x; tile[h][d0 + 1] = val.y;
        tile[h][d0 + 2] = val.z; tile[h][d0 + 3] = val.w;
    }
    __syncthreads();
#pragma unroll
    for (int i = 0; i < 4; ++i) {
        const int f = (tid + i * 256) * 4;
        const int d = f >> 6, h0 = f & 63;
        us4 o; o.x = tile[h0][d]; o.y = tile[h0 + 1][d];
        o.z = tile[h0 + 2][d]; o.w = tile[h0 + 3][d];
        *(us4*)&dst[cb + w * WD + d * 64 + h0] = o;
    }
}

// ---------------- fused W+D attention: block (s=bx, hh=by) -------------------
// All loads contiguous: phase0 from (qT,kT,vT), phase1 from (q,k,v);
// both use element offset c*HWD + hh*WD + s*64 + j.
__global__ __launch_bounds__(256) void cc_wd_kernel(
    const bf16_t* __restrict__ q,  const bf16_t* __restrict__ k,
    const bf16_t* __restrict__ v,
    const bf16_t* __restrict__ qT, const bf16_t* __restrict__ kT,
    const bf16_t* __restrict__ vT,
    const float* __restrict__ x, const float* __restrict__ gamma,
    float* __restrict__ out)
{
    const int s   = blockIdx.x;
    const int hh  = blockIdx.y;
    const int tid = threadIdx.x;
    __shared__ float qs[16][64];
    __shared__ float ks[16][64];
    __shared__ float EA[64][68];
    __shared__ float Vs[128][68];
    __shared__ float red[4][64];
    float acc[8][4];
#pragma unroll
    for (int r = 0; r < 8; ++r) { acc[r][0] = 0; acc[r][1] = 0; acc[r][2] = 0; acc[r][3] = 0; }

    const int og = tid >> 4, ng = tid & 15;
    const int dd0  = ng * 4;
    const int base = hh * WD + s * 64;

    for (int phase = 0; phase < 2; ++phase) {
        const bf16_t* qp = phase ? q : qT;
        const bf16_t* kp = phase ? k : kT;
        const bf16_t* vp = phase ? v : vT;
        __syncthreads();
        // ---- prefetch V slab into registers (consumed after softmax) ----
        us4 vreg[8];
#pragma unroll
        for (int i = 0; i < 8; ++i) {
            const int f = (tid + i * 256) * 4;
            vreg[i] = *(const us4*)&vp[(size_t)(f >> 6) * HWD + base + (f & 63)];
        }
        // ---- stage q,k ----
        {
            const int f = tid * 4, c = f >> 6, j = f & 63;
            const us4 a = *(const us4*)&qp[(size_t)c * HWD + base + j];
            qs[c][j] = b2f(a.x); qs[c][j + 1] = b2f(a.y);
            qs[c][j + 2] = b2f(a.z); qs[c][j + 3] = b2f(a.w);
            const us4 bb = *(const us4*)&kp[(size_t)c * HWD + base + j];
            ks[c][j] = b2f(bb.x); ks[c][j + 1] = b2f(bb.y);
            ks[c][j + 2] = b2f(bb.z); ks[c][j + 3] = b2f(bb.w);
        }
        __syncthreads();
        {   // E[i][j] = sum_c qs[c][i] * ks[c][j]
            const int irow = tid >> 2;
            const int j0   = (tid & 3) * 16;
            float qr[16];
#pragma unroll
            for (int c = 0; c < 16; ++c) qr[c] = qs[c][irow];
#pragma unroll
            for (int jj = 0; jj < 16; ++jj) {
                const int j = j0 + jj;
                float e = 0.f;
#pragma unroll
                for (int c = 0; c < 16; ++c) e += qr[c] * ks[c][j];
                EA[irow][j] = e;
            }
        }
        __syncthreads();
        {   // column softmax (over i, per j); write transposed EA[j][i]
            const int j = tid & 63, seg = tid >> 6;
            float vals[16];
            float m = -1e30f;
#pragma unroll
            for (int i = 0; i < 16; ++i) { vals[i] = EA[seg * 16 + i][j]; m = fmaxf(m, vals[i]); }
            red[seg][j] = m;
            __syncthreads();
            m = fmaxf(fmaxf(red[0][j], red[1][j]), fmaxf(red[2][j], red[3][j]));
            float ss = 0.f;
#pragma unroll
            for (int i = 0; i < 16; ++i) { vals[i] = __expf(vals[i] - m); ss += vals[i]; }
            __syncthreads();
            red[seg][j] = ss;
            __syncthreads();
            ss = red[0][j] + red[1][j] + red[2][j] + red[3][j];
            const float inv = 1.f / ss;
#pragma unroll
            for (int i = 0; i < 16; ++i) EA[j][seg * 16 + i] = vals[i] * inv;
        }
        // ---- drain V prefetch into LDS ----
#pragma unroll
        for (int i = 0; i < 8; ++i) {
            const int f = (tid + i * 256) * 4, c = f >> 6, j = f & 63;
            Vs[c][j] = b2f(vreg[i].x); Vs[c][j + 1] = b2f(vreg[i].y);
            Vs[c][j + 2] = b2f(vreg[i].z); Vs[c][j + 3] = b2f(vreg[i].w);
        }
        __syncthreads();
        // ---- R[c][dd] += sum_j Vs[c][j] * A(dd,j) (A at EA[j][dd]) ----
        for (int j = 0; j < 64; j += 4) {
            const float4 a0 = *(const float4*)&EA[j + 0][dd0];
            const float4 a1 = *(const float4*)&EA[j + 1][dd0];
            const float4 a2 = *(const float4*)&EA[j + 2][dd0];
            const float4 a3 = *(const float4*)&EA[j + 3][dd0];
#pragma unroll
            for (int r = 0; r < 8; ++r) {
                const float4 vv = *(const float4*)&Vs[og + 16 * r][j];
                acc[r][0] += vv.x * a0.x + vv.y * a1.x + vv.z * a2.x + vv.w * a3.x;
                acc[r][1] += vv.x * a0.y + vv.y * a1.y + vv.z * a2.y + vv.w * a3.y;
                acc[r][2] += vv.x * a0.z + vv.y * a1.z + vv.z * a2.z + vv.w * a3.z;
                acc[r][3] += vv.x * a0.w + vv.y * a1.w + vv.z * a2.w + vv.w * a3.w;
            }
        }
    }
    const float g = gamma[0];
#pragma unroll
    for (int r = 0; r < 8; ++r) {
        const int c = og + 16 * r;
        const size_t o = (size_t)(2 * s + (c >> 6)) * HWD + hh * WD + (c & 63) * 64 + dd0;
        const float4 xr = *(const float4*)&x[o];
        *(float4*)&out[o] = make_float4(g * acc[r][0] + xr.x, g * acc[r][1] + xr.y,
                                        g * acc[r][2] + xr.z, g * acc[r][3] + xr.w);
    }
}

// ---------------- fused H attention: block (t=bx, ww=by) ---------------------
// Reads permuted arrays [c][w][d][h]: offset c*HWD + ww*WD + t*64 + j.
__global__ __launch_bounds__(256) void cc_h_kernel(
    const bf16_t* __restrict__ qH, const bf16_t* __restrict__ kH,
    const bf16_t* __restrict__ vH,
    const float* __restrict__ gamma, float* __restrict__ out)
{
    const int t   = blockIdx.x;
    const int ww  = blockIdx.y;
    const int tid = threadIdx.x;
    __shared__ float qs[16][64];
    __shared__ float ks[16][64];
    __shared__ float EA[64][68];
    __shared__ float Vs[128][68];
    __shared__ float red[4][64];
    float acc[8][4];
#pragma unroll
    for (int r = 0; r < 8; ++r) { acc[r][0] = 0; acc[r][1] = 0; acc[r][2] = 0; acc[r][3] = 0; }

    const int og = tid >> 4, ng = tid & 15;
    const int dd0  = ng * 4;
    const int base = ww * WD + t * 64;

    us4 vreg[8];
#pragma unroll
    for (int i = 0; i < 8; ++i) {
        const int f = (tid + i * 256) * 4;
        vreg[i] = *(const us4*)&vH[(size_t)(f >> 6) * HWD + base + (f & 63)];
    }
    {
        const int f = tid * 4, c = f >> 6, j = f & 63;
        const us4 a = *(const us4*)&qH[(size_t)c * HWD + base + j];
        qs[c][j] = b2f(a.x); qs[c][j + 1] = b2f(a.y);
        qs[c][j + 2] = b2f(a.z); qs[c][j + 3] = b2f(a.w);
        const us4 bb = *(const us4*)&kH[(size_t)c * HWD + base + j];
        ks[c][j] = b2f(bb.x); ks[c][j + 1] = b2f(bb.y);
        ks[c][j + 2] = b2f(bb.z); ks[c][j + 3] = b2f(bb.w);
    }
    __syncthreads();
    {
        const int irow = tid >> 2;
        const int j0   = (tid & 3) * 16;
        float qr[16];
#pragma unroll
        for (int c = 0; c < 16; ++c) qr[c] = qs[c][irow];
#pragma unroll
        for (int jj = 0; jj < 16; ++jj) {
            const int j = j0 + jj;
            float e = 0.f;
#pragma unroll
            for (int c = 0; c < 16; ++c) e += qr[c] * ks[c][j];
            if (irow == j) e = -1e30f;       // diagonal mask
            EA[irow][j] = e;
        }
    }
    __syncthreads();
    {
        const int j = tid & 63, seg = tid >> 6;
        float vals[16];
        float m = -1e30f;
#pragma unroll
        for (int i = 0; i < 16; ++i) { vals[i] = EA[seg * 16 + i][j]; m = fmaxf(m, vals[i]); }
        red[seg][j] = m;
        __syncthreads();
        m = fmaxf(fmaxf(red[0][j], red[1][j]), fmaxf(red[2][j], red[3][j]));
        float ss = 0.f;
#pragma unroll
        for (int i = 0; i < 16; ++i) { vals[i] = __expf(vals[i] - m); ss += vals[i]; }
        __syncthreads();
        red[seg][j] = ss;
        __syncthreads();
        ss = red[0][j] + red[1][j] + red[2][j] + red[3][j];
        const float inv = 1.f / ss;
#pragma unroll
        for (int i = 0; i < 16; ++i) EA[j][seg * 16 + i] = vals[i] * inv;
    }
#pragma unroll
    for (int i = 0; i < 8; ++i) {
        const int f = (tid + i * 256) * 4, c = f >> 6, j = f & 63;
        Vs[c][j] = b2f(vreg[i].x); Vs[c][j + 1] = b2f(vreg[i].y);
        Vs[c][j + 2] = b2f(vreg[i].z); Vs[c][j + 3] = b2f(vreg[i].w);
    }
    __syncthreads();
    for (int j = 0; j < 64; j += 4) {
        const float4 a0 = *(const float4*)&EA[j + 0][dd0];
        const float4 a1 = *(const float4*)&EA[j + 1][dd0];
        const float4 a2 = *(const float4*)&EA[j + 2][dd0];
        const float4 a3 = *(const float4*)&EA[j + 3][dd0];
#pragma unroll
        for (int r = 0; r < 8; ++r) {
            const float4 vv = *(const float4*)&Vs[og + 16 * r][j];
            acc[r][0] += vv.x * a0.x + vv.y * a1.x + vv.z * a2.x + vv.w * a3.x;
            acc[r][1] += vv.x * a0.y + vv.y * a1.y + vv.z * a2.y + vv.w * a3.y;
            acc[r][2] += vv.x * a0.z + vv.y * a1.z + vv.z * a2.z + vv.w * a3.z;
            acc[r][3] += vv.x * a0.w + vv.y * a1.w + vv.z * a2.w + vv.w * a3.w;
        }
    }
    const float g = gamma[0];
#pragma unroll
    for (int r = 0; r < 8; ++r) {
        const int c = og + 16 * r;
        const size_t o = (size_t)(2 * t + (c >> 6)) * HWD + (c & 63) * WD + ww * 64 + dd0;
        float4 pr = *(const float4*)&out[o];
        pr.x += g * acc[r][0]; pr.y += g * acc[r][1];
        pr.z += g * acc[r][2]; pr.w += g * acc[r][3];
        *(float4*)&out[o] = pr;
    }
}

extern "C" void kernel_launch(void* const* d_in, const int* in_sizes, int n_in,
                              void* d_out, int out_size, void* d_ws, size_t ws_size,
                              hipStream_t stream)
{
    const float* x     = (const float*)d_in[0];
    const float* y     = (const float*)d_in[1];
    const float* Wq    = (const float*)d_in[2];
    const float* bq    = (const float*)d_in[3];
    const float* Wk    = (const float*)d_in[4];
    const float* bk    = (const float*)d_in[5];
    const float* Wv    = (const float*)d_in[6];
    const float* bv    = (const float*)d_in[7];
    const float* gamma = (const float*)d_in[8];
    float* out = (float*)d_out;

    // ws layout (bf16): A0 = [v(128ch)|q(16)|k(16)], A1 = wd-transposed, A2 = hd-permuted
    bf16_t* A0 = (bf16_t*)d_ws;
    bf16_t* v  = A0;
    bf16_t* q  = A0 + (size_t)128 * HWD;
    bf16_t* k  = A0 + (size_t)144 * HWD;
    bf16_t* A1 = A0 + (size_t)160 * HWD;
    bf16_t* A2 = A1 + (size_t)160 * HWD;   // total 240 MiB

    conv_v_kernel <<<4096, 256, 0, stream>>>(x, Wv, bv, v);
    conv_qk_kernel<<<dim3(512, 2), 256, 0, stream>>>(x, y, Wq, bq, Wk, bk, q, k);
    t_wd_kernel   <<<dim3(64, 160), 256, 0, stream>>>(A0, A1);
    t_hd_kernel   <<<dim3(64, 160), 256, 0, stream>>>(A0, A2);
    cc_wd_kernel  <<<dim3(64, 64), 256, 0, stream>>>(
        q, k, v, A1 + (size_t)128 * HWD, A1 + (size_t)144 * HWD, A1, x, gamma, out);
    cc_h_kernel   <<<dim3(64, 64), 256, 0, stream>>>(
        A2 + (size_t)128 * HWD, A2 + (size_t)144 * HWD, A2, gamma, out);
}